// Round 1
// baseline (534.798 us; speedup 1.0000x reference)
//
#include <hip/hip_runtime.h>

// BiasedCrossAttention: B=2, LQ=LK=1024, D=1024, H=16, DH=64, fp32.
// Round 1: correct fp32 baseline.
//   ws layout (floats): Qh[2M] | Kh[2M] | Vh[2M] | attnout[2M]  = 32 MB total.

constexpr int Bb  = 2;
constexpr int LQc = 1024;
constexpr int LKc = 1024;
constexpr int Dc  = 1024;
constexpr int Hc  = 16;
constexpr int DHc = 64;

#define NEG_BIG (-3.0e38f)

// Y = X @ W^T + bias.  X:[M,K] row-major, W:[N,K] row-major, M=2048, N=1024.
// SPLIT_HEADS: write Y[m, n] to [b, h, l, dh] layout (n tile == one head since BN=64=DH).
template <bool SPLIT_HEADS>
__global__ __launch_bounds__(256) void gemm_xwT(const float* __restrict__ X,
                                                const float* __restrict__ W,
                                                const float* __restrict__ bias,
                                                float* __restrict__ Y, int K) {
  __shared__ float As[16][68];  // [k][m], pad 68: transpose-scatter writes 2-way, float4 reads aligned
  __shared__ float Bs[16][68];  // [k][n]

  const int t  = threadIdx.x;
  const int tx = t & 15;
  const int ty = t >> 4;
  const int m0 = blockIdx.y * 64;
  const int n0 = blockIdx.x * 64;

  const int lm  = t >> 2;        // 0..63
  const int lk4 = (t & 3) * 4;   // 0,4,8,12

  const float* Xp = X + (size_t)(m0 + lm) * K + lk4;
  const float* Wp = W + (size_t)(n0 + lm) * K + lk4;

  float acc[4][4] = {};

  for (int k0 = 0; k0 < K; k0 += 16) {
    const float4 xa = *(const float4*)(Xp + k0);
    const float4 wb = *(const float4*)(Wp + k0);
    __syncthreads();
    As[lk4 + 0][lm] = xa.x; As[lk4 + 1][lm] = xa.y;
    As[lk4 + 2][lm] = xa.z; As[lk4 + 3][lm] = xa.w;
    Bs[lk4 + 0][lm] = wb.x; Bs[lk4 + 1][lm] = wb.y;
    Bs[lk4 + 2][lm] = wb.z; Bs[lk4 + 3][lm] = wb.w;
    __syncthreads();
#pragma unroll
    for (int k = 0; k < 16; ++k) {
      const float4 a = *(const float4*)&As[k][ty * 4];
      const float4 b = *(const float4*)&Bs[k][tx * 4];
      const float av[4] = {a.x, a.y, a.z, a.w};
      const float bv[4] = {b.x, b.y, b.z, b.w};
#pragma unroll
      for (int i = 0; i < 4; ++i)
#pragma unroll
        for (int j = 0; j < 4; ++j) acc[i][j] += av[i] * bv[j];
    }
  }

  const float4 bj = *(const float4*)&bias[n0 + tx * 4];
  const float bvv[4] = {bj.x, bj.y, bj.z, bj.w};
#pragma unroll
  for (int i = 0; i < 4; ++i) {
    const int m = m0 + ty * 4 + i;
    float4 o;
    o.x = acc[i][0] + bvv[0];
    o.y = acc[i][1] + bvv[1];
    o.z = acc[i][2] + bvv[2];
    o.w = acc[i][3] + bvv[3];
    if (SPLIT_HEADS) {
      const int b = m >> 10;       // m = b*LQ + l
      const int l = m & 1023;
      const int h = n0 >> 6;       // n tile == head
      float* dst = Y + ((size_t)((b * Hc + h) * LQc + l)) * DHc + tx * 4;
      *(float4*)dst = o;
    } else {
      *(float4*)&Y[(size_t)m * Dc + n0 + tx * 4] = o;
    }
  }
}

// Flash-style attention. Grid: (LQ/64, B*H). Block 256 = 16x16, each thread 4x4.
__global__ __launch_bounds__(256) void flash_attn(const float* __restrict__ Qh,
                                                  const float* __restrict__ Kh,
                                                  const float* __restrict__ Vh,
                                                  const float* __restrict__ biasL,
                                                  const int* __restrict__ kpm,
                                                  float* __restrict__ Yout) {
  __shared__ float Qst[64][68];  // [k][r]   (k = head dim)
  __shared__ float Kst[64][68];  // [k][c]
  __shared__ float Vs[64][64];   // [j][d]
  __shared__ float Ps[64][64];   // [r][c]

  const int t  = threadIdx.x;
  const int tx = t & 15;
  const int ty = t >> 4;
  const int q0 = blockIdx.x * 64;
  const int bh = blockIdx.y;  // b*H + h
  const int b  = bh >> 4;
  const int h  = bh & 15;

  // Stage Q tile transposed (k-major).
#pragma unroll
  for (int it = 0; it < 4; ++it) {
    const int row = (t >> 4) + it * 16;
    const int c4  = (t & 15) * 4;
    const float4 qv =
        *(const float4*)&Qh[((size_t)(bh * LQc + q0 + row)) * DHc + c4];
    Qst[c4 + 0][row] = qv.x; Qst[c4 + 1][row] = qv.y;
    Qst[c4 + 2][row] = qv.z; Qst[c4 + 3][row] = qv.w;
  }

  float acc[4][4] = {};
  float m_i[4], l_i[4];
#pragma unroll
  for (int i = 0; i < 4; ++i) { m_i[i] = NEG_BIG; l_i[i] = 0.0f; }

  const float scale = 0.125f;  // 1/sqrt(DH)

  for (int j0 = 0; j0 < LKc; j0 += 64) {
    __syncthreads();  // protect LDS from previous iteration's readers (and Q staging on iter 0)
    // Stage K (k-major) and V (row-major) tiles.
#pragma unroll
    for (int it = 0; it < 4; ++it) {
      const int row = (t >> 4) + it * 16;
      const int c4  = (t & 15) * 4;
      const float4 kv =
          *(const float4*)&Kh[((size_t)(bh * LKc + j0 + row)) * DHc + c4];
      Kst[c4 + 0][row] = kv.x; Kst[c4 + 1][row] = kv.y;
      Kst[c4 + 2][row] = kv.z; Kst[c4 + 3][row] = kv.w;
      const float4 vv =
          *(const float4*)&Vh[((size_t)(bh * LKc + j0 + row)) * DHc + c4];
      *(float4*)&Vs[row][c4] = vv;
    }
    __syncthreads();

    // S = Q K^T (4x4 per thread)
    float s[4][4] = {};
#pragma unroll 8
    for (int k = 0; k < 64; ++k) {
      const float4 a  = *(const float4*)&Qst[k][ty * 4];
      const float4 kk = *(const float4*)&Kst[k][tx * 4];
      const float av[4] = {a.x, a.y, a.z, a.w};
      const float kv[4] = {kk.x, kk.y, kk.z, kk.w};
#pragma unroll
      for (int i = 0; i < 4; ++i)
#pragma unroll
        for (int j = 0; j < 4; ++j) s[i][j] += av[i] * kv[j];
    }

    // scale + bias + key padding mask
    const int4 mk = *(const int4*)&kpm[b * LKc + j0 + tx * 4];
    const int mkv[4] = {mk.x, mk.y, mk.z, mk.w};
#pragma unroll
    for (int i = 0; i < 4; ++i) {
      const float4 bbv4 = *(const float4*)&biasL[((size_t)(b * LQc + q0 + ty * 4 + i)) * LKc + j0 + tx * 4];
      const float bbv[4] = {bbv4.x, bbv4.y, bbv4.z, bbv4.w};
#pragma unroll
      for (int j = 0; j < 4; ++j)
        s[i][j] = mkv[j] ? NEG_BIG : s[i][j] * scale + bbv[j];
    }

    // Online softmax (row stats shared across the 16 tx lanes of each row).
#pragma unroll
    for (int i = 0; i < 4; ++i) {
      float rm = fmaxf(fmaxf(s[i][0], s[i][1]), fmaxf(s[i][2], s[i][3]));
#pragma unroll
      for (int off = 1; off < 16; off <<= 1) rm = fmaxf(rm, __shfl_xor(rm, off, 16));
      const float mn    = fmaxf(m_i[i], rm);
      const float alpha = __expf(m_i[i] - mn);
      float ps = 0.0f;
#pragma unroll
      for (int j = 0; j < 4; ++j) {
        s[i][j] = __expf(s[i][j] - mn);
        ps += s[i][j];
      }
#pragma unroll
      for (int off = 1; off < 16; off <<= 1) ps += __shfl_xor(ps, off, 16);
      l_i[i] = l_i[i] * alpha + ps;
      m_i[i] = mn;
#pragma unroll
      for (int j = 0; j < 4; ++j) acc[i][j] *= alpha;
      float4 pv;
      pv.x = s[i][0]; pv.y = s[i][1]; pv.z = s[i][2]; pv.w = s[i][3];
      *(float4*)&Ps[ty * 4 + i][tx * 4] = pv;
    }
    __syncthreads();

    // O += P V
#pragma unroll 4
    for (int jb = 0; jb < 64; jb += 4) {
      float4 vrow[4];
#pragma unroll
      for (int jj = 0; jj < 4; ++jj) vrow[jj] = *(const float4*)&Vs[jb + jj][tx * 4];
#pragma unroll
      for (int i = 0; i < 4; ++i) {
        const float4 p = *(const float4*)&Ps[ty * 4 + i][jb];
        const float pv[4] = {p.x, p.y, p.z, p.w};
#pragma unroll
        for (int jj = 0; jj < 4; ++jj) {
          acc[i][0] += pv[jj] * vrow[jj].x;
          acc[i][1] += pv[jj] * vrow[jj].y;
          acc[i][2] += pv[jj] * vrow[jj].z;
          acc[i][3] += pv[jj] * vrow[jj].w;
        }
      }
    }
  }

  // Epilogue: divide by l, write merged-head layout [B, LQ, D].
#pragma unroll
  for (int i = 0; i < 4; ++i) {
    const float inv = 1.0f / l_i[i];
    float4 o;
    o.x = acc[i][0] * inv;
    o.y = acc[i][1] * inv;
    o.z = acc[i][2] * inv;
    o.w = acc[i][3] * inv;
    const int qrow = q0 + ty * 4 + i;
    *(float4*)&Yout[((size_t)(b * LQc + qrow)) * Dc + h * DHc + tx * 4] = o;
  }
}

extern "C" void kernel_launch(void* const* d_in, const int* in_sizes, int n_in,
                              void* d_out, int out_size, void* d_ws, size_t ws_size,
                              hipStream_t stream) {
  (void)in_sizes; (void)n_in; (void)out_size; (void)ws_size;
  const float* q   = (const float*)d_in[0];
  const float* k   = (const float*)d_in[1];
  const float* v   = (const float*)d_in[2];
  const float* Wq  = (const float*)d_in[3];
  const float* bq  = (const float*)d_in[4];
  const float* Wk  = (const float*)d_in[5];
  const float* bk  = (const float*)d_in[6];
  const float* Wv  = (const float*)d_in[7];
  const float* bv  = (const float*)d_in[8];
  const float* Wo  = (const float*)d_in[9];
  const float* bo  = (const float*)d_in[10];
  const float* lb  = (const float*)d_in[11];
  const int*   kpm = (const int*)d_in[12];
  float* out = (float*)d_out;

  const size_t NT = (size_t)Bb * Hc * LQc * DHc;  // 2,097,152 floats
  float* Qh = (float*)d_ws;
  float* Kh = Qh + NT;
  float* Vh = Kh + NT;
  float* AO = Vh + NT;  // attention output, merged heads [B, LQ, D]

  const dim3 gg(Dc / 64, (Bb * LQc) / 64);  // (16, 32)
  gemm_xwT<true><<<gg, 256, 0, stream>>>(q, Wq, bq, Qh, Dc);
  gemm_xwT<true><<<gg, 256, 0, stream>>>(k, Wk, bk, Kh, Dc);
  gemm_xwT<true><<<gg, 256, 0, stream>>>(v, Wv, bv, Vh, Dc);
  flash_attn<<<dim3(LQc / 64, Bb * Hc), 256, 0, stream>>>(Qh, Kh, Vh, lb, kpm, AO);
  gemm_xwT<false><<<gg, 256, 0, stream>>>(AO, Wo, bo, out, Dc);
}

// Round 2
// 200.739 us; speedup vs baseline: 2.6642x; 2.6642x over previous
//
#include <hip/hip_runtime.h>

// BiasedCrossAttention B=2, LQ=LK=1024, D=1024, H=16, DH=64. fp32 in/out.
// R2: full fp16-MFMA pipeline (16x16x32), global_load_lds staging, XOR-swizzled LDS.
// ws (halves): q16|k16|v16|Qh|Kh|Vt  = 6 * 2M halves = 24 MB. AO aliases q16.

typedef _Float16 half8 __attribute__((ext_vector_type(8)));
typedef float f32x4 __attribute__((ext_vector_type(4)));

#define MFMA16(a, b, c) __builtin_amdgcn_mfma_f32_16x16x32_f16((a), (b), (c), 0, 0, 0)

__device__ __forceinline__ void gload16(const void* g, void* l) {
  __builtin_amdgcn_global_load_lds(
      (const __attribute__((address_space(1))) unsigned int*)g,
      (__attribute__((address_space(3))) unsigned int*)l, 16, 0, 0);
}

// Tiles are rows of 64 halves (128 B = 8 chunks of 16 B), chunk-swizzled:
// physical chunk = logical chunk ^ (row & 7).  Conflict-free b128 frag reads
// AND compatible with global_load_lds's lane-contiguous LDS placement.
__device__ __forceinline__ half8 frag_ld(const _Float16* t, int row, int ck) {
  return *(const half8*)(t + row * 64 + (((ck ^ (row & 7)) << 3)));
}

// ---------------------------------------------------------------- cvt fp32->fp16
__global__ __launch_bounds__(256) void cvt_f32_f16(
    const float* __restrict__ q, const float* __restrict__ k, const float* __restrict__ v,
    _Float16* __restrict__ q16, _Float16* __restrict__ k16, _Float16* __restrict__ v16) {
  const float* s;
  _Float16* d;
  if (blockIdx.y == 0) { s = q; d = q16; }
  else if (blockIdx.y == 1) { s = k; d = k16; }
  else { s = v; d = v16; }
  const size_t i = ((size_t)blockIdx.x * 256 + threadIdx.x) * 8;
  const float4 a = *(const float4*)(s + i);
  const float4 b = *(const float4*)(s + i + 4);
  half8 h;
  h[0] = (_Float16)a.x; h[1] = (_Float16)a.y; h[2] = (_Float16)a.z; h[3] = (_Float16)a.w;
  h[4] = (_Float16)b.x; h[5] = (_Float16)b.y; h[6] = (_Float16)b.z; h[7] = (_Float16)b.w;
  *(half8*)(d + i) = h;
}

// ---------------------------------------------------------------- GEMM C = X @ W^T + bias
// X fp16 [2048][1024] (async staged), W fp32 [1024][1024] (VALU-converted staging).
// 128x128 tile, BK=64, 4 waves, each wave 64x64 (4x4 of 16x16x32 MFMA).
// Epilogues: is_final -> fp32 row-major out; z<2 -> split-head fp16 [bh][l][dh];
//            z==2 -> LDS transpose -> Vt fp16 [bh][dh][l].
__global__ __launch_bounds__(256) void mm_bt(
    const _Float16* __restrict__ Aq, const _Float16* __restrict__ Ak,
    const _Float16* __restrict__ Av, const float* __restrict__ W0,
    const float* __restrict__ W1, const float* __restrict__ W2,
    const float* __restrict__ c0, const float* __restrict__ c1,
    const float* __restrict__ c2, _Float16* __restrict__ Dq,
    _Float16* __restrict__ Dk, _Float16* __restrict__ Dvt,
    float* __restrict__ Df, int is_final) {
  __shared__ __align__(16) _Float16 lds[17408];  // As(8192) | Bs(8192); reused as Ct[128][136]
  _Float16* As = lds;
  _Float16* Bs = lds + 8192;

  const int tid = threadIdx.x;
  const int wv = tid >> 6, ln = tid & 63;
  const int quad = ln >> 4, col = ln & 15;
  const int wm = wv >> 1, wn = wv & 1;
  const int n0 = blockIdx.x * 128;
  const int m0 = blockIdx.y * 128;
  const int z = blockIdx.z;

  const _Float16* A = (z == 0) ? Aq : (z == 1) ? Ak : Av;
  const float* Bw = (z == 0) ? W0 : (z == 1) ? W1 : W2;
  const float* bias = (z == 0) ? c0 : (z == 1) ? c1 : c2;

  const f32x4 zero4 = {0.f, 0.f, 0.f, 0.f};
  f32x4 acc[4][4];
#pragma unroll
  for (int i = 0; i < 4; ++i)
#pragma unroll
    for (int j = 0; j < 4; ++j) acc[i][j] = zero4;

  for (int k0 = 0; k0 < 1024; k0 += 64) {
    __syncthreads();
    // A tile: 128 rows x 8 chunks = 1024 chunks, 4 async issues
#pragma unroll
    for (int j = 0; j < 4; ++j) {
      const int ci = j * 256 + wv * 64 + ln;
      const int row = ci >> 3;
      const int lc = (ci & 7) ^ (row & 7);
      gload16(A + (size_t)(m0 + row) * 1024 + k0 + lc * 8,
              As + (size_t)(j * 256 + wv * 64) * 8);
    }
    // B tile: fp32 -> fp16 VALU staging (same swizzle)
#pragma unroll
    for (int j = 0; j < 4; ++j) {
      const int ci = j * 256 + tid;
      const int row = ci >> 3;
      const int lc = (ci & 7) ^ (row & 7);
      const float* sp = Bw + (size_t)(n0 + row) * 1024 + k0 + lc * 8;
      const float4 u = *(const float4*)sp;
      const float4 w = *(const float4*)(sp + 4);
      half8 h;
      h[0] = (_Float16)u.x; h[1] = (_Float16)u.y; h[2] = (_Float16)u.z; h[3] = (_Float16)u.w;
      h[4] = (_Float16)w.x; h[5] = (_Float16)w.y; h[6] = (_Float16)w.z; h[7] = (_Float16)w.w;
      *(half8*)(Bs + (size_t)ci * 8) = h;
    }
    __syncthreads();
#pragma unroll
    for (int kk = 0; kk < 2; ++kk) {
      half8 af[4], bf[4];
#pragma unroll
      for (int mi = 0; mi < 4; ++mi)
        af[mi] = frag_ld(As, wm * 64 + mi * 16 + col, kk * 4 + quad);
#pragma unroll
      for (int ni = 0; ni < 4; ++ni)
        bf[ni] = frag_ld(Bs, wn * 64 + ni * 16 + col, kk * 4 + quad);
#pragma unroll
      for (int mi = 0; mi < 4; ++mi)
#pragma unroll
        for (int ni = 0; ni < 4; ++ni)
          acc[mi][ni] = MFMA16(af[mi], bf[ni], acc[mi][ni]);
    }
  }

  // bias per output column n
  float bv[4];
#pragma unroll
  for (int ni = 0; ni < 4; ++ni) bv[ni] = bias[n0 + wn * 64 + ni * 16 + col];

  if (is_final) {
#pragma unroll
    for (int mi = 0; mi < 4; ++mi) {
      const int m_g = m0 + wm * 64 + mi * 16 + quad * 4;
#pragma unroll
      for (int ni = 0; ni < 4; ++ni) {
        const int n_g = n0 + wn * 64 + ni * 16 + col;
#pragma unroll
        for (int r = 0; r < 4; ++r)
          Df[(size_t)(m_g + r) * 1024 + n_g] = acc[mi][ni][r] + bv[ni];
      }
    }
  } else if (z < 2) {
    _Float16* D = z ? Dk : Dq;
#pragma unroll
    for (int mi = 0; mi < 4; ++mi) {
      const int m_g = m0 + wm * 64 + mi * 16 + quad * 4;
#pragma unroll
      for (int ni = 0; ni < 4; ++ni) {
        const int n_g = n0 + wn * 64 + ni * 16 + col;
        const int h = n_g >> 6, dh = n_g & 63;
#pragma unroll
        for (int r = 0; r < 4; ++r) {
          const int b = (m_g + r) >> 10, l = (m_g + r) & 1023;
          D[((size_t)((b * 16 + h) * 1024) + l) * 64 + dh] =
              (_Float16)(acc[mi][ni][r] + bv[ni]);
        }
      }
    }
  } else {
    // transpose 128x128 through LDS, write Vt[bh][dh][l] with coalesced half8 rows
    __syncthreads();
    _Float16* Ct = lds;  // [128][136] (pad keeps 16B alignment, 2-way banks)
#pragma unroll
    for (int mi = 0; mi < 4; ++mi) {
      const int ml = wm * 64 + mi * 16 + quad * 4;
#pragma unroll
      for (int ni = 0; ni < 4; ++ni) {
        const int nl = wn * 64 + ni * 16 + col;
#pragma unroll
        for (int r = 0; r < 4; ++r)
          Ct[(size_t)nl * 136 + ml + r] = (_Float16)(acc[mi][ni][r] + bv[ni]);
      }
    }
    __syncthreads();
#pragma unroll
    for (int it = 0; it < 8; ++it) {
      const int ci = it * 256 + tid;
      const int n = ci >> 4;
      const int mc = (ci & 15) * 8;
      const half8 hv = *(const half8*)(Ct + (size_t)n * 136 + mc);
      const int n_g = n0 + n;
      const int h = n_g >> 6, dh = n_g & 63;
      const int m_g = m0 + mc;
      const int b = m_g >> 10, l = m_g & 1023;
      *(half8*)(Dvt + ((size_t)((b * 16 + h) * 64 + dh)) * 1024 + l) = hv;
    }
  }
}

// ---------------------------------------------------------------- flash attention
// grid (LQ/64, B*H), 256 thr = 4 waves; wave w owns q-rows [w*16, w*16+16).
__global__ __launch_bounds__(256) void attn(
    const _Float16* __restrict__ Qh, const _Float16* __restrict__ Kh,
    const _Float16* __restrict__ Vt, const float* __restrict__ biasL,
    const int* __restrict__ kpm, _Float16* __restrict__ AO) {
  __shared__ __align__(16) _Float16 Qs[4096];
  __shared__ __align__(16) _Float16 Ks[4096];
  __shared__ __align__(16) _Float16 Vs[4096];  // [dh][l-local], from Vt
  __shared__ __align__(16) _Float16 Ps[4][1024];

  const int tid = threadIdx.x;
  const int wv = tid >> 6, ln = tid & 63;
  const int quad = ln >> 4, col = ln & 15;
  const int q0 = blockIdx.x * 64;
  const int bh = blockIdx.y;
  const int b = bh >> 4, hh = bh & 15;
  const int qrow_base = q0 + wv * 16 + quad * 4;

  // stage Q once (64 rows x 8 chunks = 512 chunks, 2 issues)
#pragma unroll
  for (int j = 0; j < 2; ++j) {
    const int ci = j * 256 + wv * 64 + ln;
    const int row = ci >> 3;
    const int lc = (ci & 7) ^ (row & 7);
    gload16(Qh + ((size_t)bh * 1024 + q0 + row) * 64 + lc * 8,
            Qs + (size_t)(j * 256 + wv * 64) * 8);
  }

  const f32x4 zero4 = {0.f, 0.f, 0.f, 0.f};
  f32x4 o[4];
#pragma unroll
  for (int ni = 0; ni < 4; ++ni) o[ni] = zero4;
  float m_i[4] = {-1e30f, -1e30f, -1e30f, -1e30f};
  float l_i[4] = {0.f, 0.f, 0.f, 0.f};

  for (int k0 = 0; k0 < 1024; k0 += 64) {
    __syncthreads();
#pragma unroll
    for (int j = 0; j < 2; ++j) {
      const int ci = j * 256 + wv * 64 + ln;
      const int row = ci >> 3;
      const int lc = (ci & 7) ^ (row & 7);
      gload16(Kh + ((size_t)bh * 1024 + k0 + row) * 64 + lc * 8,
              Ks + (size_t)(j * 256 + wv * 64) * 8);
      gload16(Vt + ((size_t)(bh * 64 + row)) * 1024 + k0 + lc * 8,
              Vs + (size_t)(j * 256 + wv * 64) * 8);
    }
    // bias + mask straight from global (each element used once) — overlaps DMA
    float bb[4][4];
    int mk[4];
#pragma unroll
    for (int ni = 0; ni < 4; ++ni) {
      const int kg = k0 + ni * 16 + col;
      mk[ni] = kpm[b * 1024 + kg];
#pragma unroll
      for (int r = 0; r < 4; ++r)
        bb[ni][r] = biasL[((size_t)(b * 1024 + qrow_base + r)) * 1024 + kg];
    }
    __syncthreads();

    // S = Q K^T
    const half8 aq0 = frag_ld(Qs, wv * 16 + col, quad);
    const half8 aq1 = frag_ld(Qs, wv * 16 + col, 4 + quad);
    f32x4 s[4];
#pragma unroll
    for (int ni = 0; ni < 4; ++ni) {
      f32x4 z4 = zero4;
      const half8 b0 = frag_ld(Ks, ni * 16 + col, quad);
      const half8 b1 = frag_ld(Ks, ni * 16 + col, 4 + quad);
      z4 = MFMA16(aq0, b0, z4);
      z4 = MFMA16(aq1, b1, z4);
      s[ni] = z4;
    }

#pragma unroll
    for (int ni = 0; ni < 4; ++ni)
#pragma unroll
      for (int r = 0; r < 4; ++r)
        s[ni][r] = mk[ni] ? -1e9f : (s[ni][r] * 0.125f + bb[ni][r]);

    // online softmax (row r lives on the 16 lanes of this quad)
    float alpha[4];
#pragma unroll
    for (int r = 0; r < 4; ++r) {
      float rm = fmaxf(fmaxf(s[0][r], s[1][r]), fmaxf(s[2][r], s[3][r]));
#pragma unroll
      for (int off = 1; off < 16; off <<= 1) rm = fmaxf(rm, __shfl_xor(rm, off, 16));
      const float mn = fmaxf(m_i[r], rm);
      alpha[r] = __expf(m_i[r] - mn);
      m_i[r] = mn;
      float ps = 0.f;
#pragma unroll
      for (int ni = 0; ni < 4; ++ni) {
        const float p = __expf(s[ni][r] - mn);
        s[ni][r] = p;
        ps += p;
      }
#pragma unroll
      for (int off = 1; off < 16; off <<= 1) ps += __shfl_xor(ps, off, 16);
      l_i[r] = l_i[r] * alpha[r] + ps;
    }
#pragma unroll
    for (int ni = 0; ni < 4; ++ni)
#pragma unroll
      for (int r = 0; r < 4; ++r) o[ni][r] *= alpha[r];

    // P -> LDS (C-layout -> A-operand layout round trip), swizzled rows
    _Float16* Pw = Ps[wv];
#pragma unroll
    for (int ni = 0; ni < 4; ++ni)
#pragma unroll
      for (int r = 0; r < 4; ++r) {
        const int row = quad * 4 + r;
        const int k = ni * 16 + col;
        Pw[row * 64 + ((((k >> 3) ^ (row & 7)) << 3) | (k & 7))] = (_Float16)s[ni][r];
      }
    __syncthreads();

    // O += P V   (B-operand = Vs rows are dh, k-contiguous)
    const half8 ap0 = frag_ld(Pw, col, quad);
    const half8 ap1 = frag_ld(Pw, col, 4 + quad);
#pragma unroll
    for (int ni = 0; ni < 4; ++ni) {
      const half8 b0 = frag_ld(Vs, ni * 16 + col, quad);
      const half8 b1 = frag_ld(Vs, ni * 16 + col, 4 + quad);
      o[ni] = MFMA16(ap0, b0, o[ni]);
      o[ni] = MFMA16(ap1, b1, o[ni]);
    }
  }

  // epilogue: /l, write merged heads fp16 [b][q][D]
#pragma unroll
  for (int r = 0; r < 4; ++r) {
    const float inv = 1.0f / l_i[r];
    const int qg = qrow_base + r;
#pragma unroll
    for (int ni = 0; ni < 4; ++ni) {
      const int dh = ni * 16 + col;
      AO[((size_t)(b * 1024 + qg)) * 1024 + hh * 64 + dh] = (_Float16)(o[ni][r] * inv);
    }
  }
}

extern "C" void kernel_launch(void* const* d_in, const int* in_sizes, int n_in,
                              void* d_out, int out_size, void* d_ws, size_t ws_size,
                              hipStream_t stream) {
  (void)in_sizes; (void)n_in; (void)out_size; (void)ws_size;
  const float* q = (const float*)d_in[0];
  const float* k = (const float*)d_in[1];
  const float* v = (const float*)d_in[2];
  const float* Wq = (const float*)d_in[3];
  const float* bq = (const float*)d_in[4];
  const float* Wk = (const float*)d_in[5];
  const float* bk = (const float*)d_in[6];
  const float* Wv = (const float*)d_in[7];
  const float* bv = (const float*)d_in[8];
  const float* Wo = (const float*)d_in[9];
  const float* bo = (const float*)d_in[10];
  const float* lb = (const float*)d_in[11];
  const int* kpm = (const int*)d_in[12];
  float* out = (float*)d_out;

  const size_t NT = (size_t)2 * 1024 * 1024;  // 2M halves per tensor
  _Float16* q16 = (_Float16*)d_ws;
  _Float16* k16 = q16 + NT;
  _Float16* v16 = k16 + NT;
  _Float16* Qh = v16 + NT;
  _Float16* Kh = Qh + NT;
  _Float16* Vt = Kh + NT;
  _Float16* AO = q16;  // q16 dead after projections

  cvt_f32_f16<<<dim3(1024, 3), 256, 0, stream>>>(q, k, v, q16, k16, v16);
  mm_bt<<<dim3(8, 16, 3), 256, 0, stream>>>(q16, k16, v16, Wq, Wk, Wv, bq, bk, bv,
                                            Qh, Kh, Vt, nullptr, 0);
  attn<<<dim3(16, 32), 256, 0, stream>>>(Qh, Kh, Vt, lb, kpm, AO);
  mm_bt<<<dim3(8, 16, 1), 256, 0, stream>>>(AO, nullptr, nullptr, Wo, nullptr, nullptr,
                                            bo, nullptr, nullptr, nullptr, nullptr,
                                            nullptr, out, 1);
}

// Round 3
// 185.599 us; speedup vs baseline: 2.8815x; 1.0816x over previous
//
#include <hip/hip_runtime.h>

// BiasedCrossAttention B=2, LQ=LK=1024, D=1024, H=16, DH=64. fp32 in/out.
// R3: S^T/O^T attention (per-lane softmax rows, vector bias loads, b64 P-stores,
//     no P barrier), weights pre-converted to fp16 (async B staging in GEMMs).
// ws (halves, 32 MB): q16|k16|v16 (2M ea) | Qh|Kh|Vt (2M ea) | W16 (4x1M).

typedef _Float16 half8 __attribute__((ext_vector_type(8)));
typedef _Float16 half4_t __attribute__((ext_vector_type(4)));
typedef float f32x4 __attribute__((ext_vector_type(4)));

#define MFMA16(a, b, c) __builtin_amdgcn_mfma_f32_16x16x32_f16((a), (b), (c), 0, 0, 0)

__device__ __forceinline__ void gload16(const void* g, void* l) {
  __builtin_amdgcn_global_load_lds(
      (const __attribute__((address_space(1))) unsigned int*)g,
      (__attribute__((address_space(3))) unsigned int*)l, 16, 0, 0);
}

// Rows of 64 halves (8 x 16B chunks), physical chunk = logical ^ (row & 7).
__device__ __forceinline__ half8 frag_ld(const _Float16* t, int row, int ck) {
  return *(const half8*)(t + row * 64 + (((ck ^ (row & 7)) << 3)));
}

// ------------------------------------------------- cvt fp32->fp16 (acts + weights)
__global__ __launch_bounds__(256) void cvt_f32_f16(
    const float* __restrict__ q, const float* __restrict__ k, const float* __restrict__ v,
    const float* __restrict__ Wq, const float* __restrict__ Wk,
    const float* __restrict__ Wv, const float* __restrict__ Wo,
    _Float16* __restrict__ q16, _Float16* __restrict__ k16, _Float16* __restrict__ v16,
    _Float16* __restrict__ w16) {
  const int y = blockIdx.y;
  if (y >= 3 && blockIdx.x >= 512) return;  // weights are 1M elems (512 blocks)
  const float* s;
  _Float16* d;
  const size_t M = (size_t)1024 * 1024;
  switch (y) {
    case 0: s = q;  d = q16; break;
    case 1: s = k;  d = k16; break;
    case 2: s = v;  d = v16; break;
    case 3: s = Wq; d = w16; break;
    case 4: s = Wk; d = w16 + M; break;
    case 5: s = Wv; d = w16 + 2 * M; break;
    default: s = Wo; d = w16 + 3 * M; break;
  }
  const size_t i = ((size_t)blockIdx.x * 256 + threadIdx.x) * 8;
  const float4 a = *(const float4*)(s + i);
  const float4 bvv = *(const float4*)(s + i + 4);
  half8 h;
  h[0] = (_Float16)a.x; h[1] = (_Float16)a.y; h[2] = (_Float16)a.z; h[3] = (_Float16)a.w;
  h[4] = (_Float16)bvv.x; h[5] = (_Float16)bvv.y; h[6] = (_Float16)bvv.z; h[7] = (_Float16)bvv.w;
  *(half8*)(d + i) = h;
}

// ------------------------------------------------- GEMM C = X @ W^T + bias (all fp16 in)
// 128x128 tile, BK=64, 4 waves x (64x64). Both operands via global_load_lds.
__global__ __launch_bounds__(256) void mm_bt(
    const _Float16* __restrict__ Aq, const _Float16* __restrict__ Ak,
    const _Float16* __restrict__ Av, const _Float16* __restrict__ W16,
    const float* __restrict__ c0, const float* __restrict__ c1,
    const float* __restrict__ c2, _Float16* __restrict__ Dq,
    _Float16* __restrict__ Dk, _Float16* __restrict__ Dvt,
    float* __restrict__ Df, int is_final) {
  __shared__ __align__(16) _Float16 lds[17408];  // As(8192) | Bs(8192); reused as Ct[128][136]
  _Float16* As = lds;
  _Float16* Bs = lds + 8192;

  const int tid = threadIdx.x;
  const int wv = tid >> 6, ln = tid & 63;
  const int quad = ln >> 4, col = ln & 15;
  const int wm = wv >> 1, wn = wv & 1;
  const int n0 = blockIdx.x * 128;
  const int m0 = blockIdx.y * 128;
  const int z = blockIdx.z;

  const _Float16* A = (z == 0) ? Aq : (z == 1) ? Ak : Av;
  const _Float16* Bw = W16 + (size_t)z * 1024 * 1024;
  const float* bias = (z == 0) ? c0 : (z == 1) ? c1 : c2;

  const f32x4 zero4 = {0.f, 0.f, 0.f, 0.f};
  f32x4 acc[4][4];
#pragma unroll
  for (int i = 0; i < 4; ++i)
#pragma unroll
    for (int j = 0; j < 4; ++j) acc[i][j] = zero4;

  for (int k0 = 0; k0 < 1024; k0 += 64) {
    __syncthreads();
#pragma unroll
    for (int j = 0; j < 4; ++j) {
      const int ci = j * 256 + wv * 64 + ln;
      const int row = ci >> 3;
      const int lc = (ci & 7) ^ (row & 7);
      gload16(A + (size_t)(m0 + row) * 1024 + k0 + lc * 8,
              As + (size_t)(j * 256 + wv * 64) * 8);
      gload16(Bw + (size_t)(n0 + row) * 1024 + k0 + lc * 8,
              Bs + (size_t)(j * 256 + wv * 64) * 8);
    }
    __syncthreads();
#pragma unroll
    for (int kk = 0; kk < 2; ++kk) {
      half8 af[4], bf[4];
#pragma unroll
      for (int mi = 0; mi < 4; ++mi)
        af[mi] = frag_ld(As, wm * 64 + mi * 16 + col, kk * 4 + quad);
#pragma unroll
      for (int ni = 0; ni < 4; ++ni)
        bf[ni] = frag_ld(Bs, wn * 64 + ni * 16 + col, kk * 4 + quad);
#pragma unroll
      for (int mi = 0; mi < 4; ++mi)
#pragma unroll
        for (int ni = 0; ni < 4; ++ni)
          acc[mi][ni] = MFMA16(af[mi], bf[ni], acc[mi][ni]);
    }
  }

  float bv[4];
#pragma unroll
  for (int ni = 0; ni < 4; ++ni) bv[ni] = bias[n0 + wn * 64 + ni * 16 + col];

  if (is_final) {
#pragma unroll
    for (int mi = 0; mi < 4; ++mi) {
      const int m_g = m0 + wm * 64 + mi * 16 + quad * 4;
#pragma unroll
      for (int ni = 0; ni < 4; ++ni) {
        const int n_g = n0 + wn * 64 + ni * 16 + col;
#pragma unroll
        for (int r = 0; r < 4; ++r)
          Df[(size_t)(m_g + r) * 1024 + n_g] = acc[mi][ni][r] + bv[ni];
      }
    }
  } else if (z < 2) {
    _Float16* D = z ? Dk : Dq;
#pragma unroll
    for (int mi = 0; mi < 4; ++mi) {
      const int m_g = m0 + wm * 64 + mi * 16 + quad * 4;
#pragma unroll
      for (int ni = 0; ni < 4; ++ni) {
        const int n_g = n0 + wn * 64 + ni * 16 + col;
        const int h = n_g >> 6, dh = n_g & 63;
#pragma unroll
        for (int r = 0; r < 4; ++r) {
          const int b = (m_g + r) >> 10, l = (m_g + r) & 1023;
          D[((size_t)((b * 16 + h) * 1024) + l) * 64 + dh] =
              (_Float16)(acc[mi][ni][r] + bv[ni]);
        }
      }
    }
  } else {
    // transpose through LDS -> Vt[bh][dh][l]
    __syncthreads();
    _Float16* Ct = lds;  // [128][136]
#pragma unroll
    for (int mi = 0; mi < 4; ++mi) {
      const int ml = wm * 64 + mi * 16 + quad * 4;
#pragma unroll
      for (int ni = 0; ni < 4; ++ni) {
        const int nl = wn * 64 + ni * 16 + col;
#pragma unroll
        for (int r = 0; r < 4; ++r)
          Ct[(size_t)nl * 136 + ml + r] = (_Float16)(acc[mi][ni][r] + bv[ni]);
      }
    }
    __syncthreads();
#pragma unroll
    for (int it = 0; it < 8; ++it) {
      const int ci = it * 256 + tid;
      const int n = ci >> 4;
      const int mc = (ci & 15) * 8;
      const half8 hv = *(const half8*)(Ct + (size_t)n * 136 + mc);
      const int n_g = n0 + n;
      const int h = n_g >> 6, dh = n_g & 63;
      const int m_g = m0 + mc;
      const int b = m_g >> 10, l = m_g & 1023;
      *(half8*)(Dvt + ((size_t)((b * 16 + h) * 64 + dh)) * 1024 + l) = hv;
    }
  }
}

// ------------------------------------------------- flash attention, S^T/O^T form
// grid (LQ/64, B*H), 4 waves; wave wv owns q-rows [q0+wv*16, +16).
// S^T = K Q^T  : lane holds col=q, rows=keys -> softmax row entirely on one lane
//                (+2 shfl across quads).
// O^T = V^T P^T: lane col=q, rows=dh.
__global__ __launch_bounds__(256) void attn(
    const _Float16* __restrict__ Qh, const _Float16* __restrict__ Kh,
    const _Float16* __restrict__ Vt, const float* __restrict__ biasL,
    const int* __restrict__ kpm, _Float16* __restrict__ AO) {
  __shared__ __align__(16) _Float16 Qs[4096];
  __shared__ __align__(16) _Float16 Ks[4096];
  __shared__ __align__(16) _Float16 Vs[4096];   // [dh][k-local]
  __shared__ __align__(16) _Float16 Pt[4096];   // per-wave 16q x 64k, swizzled

  const int tid = threadIdx.x;
  const int wv = tid >> 6, ln = tid & 63;
  const int quad = ln >> 4, col = ln & 15;
  const int q0 = blockIdx.x * 64;
  const int bh = blockIdx.y;
  const int b = bh >> 4, hh = bh & 15;
  const int qg = q0 + wv * 16 + col;  // this lane's softmax row

  // stage Q once
#pragma unroll
  for (int j = 0; j < 2; ++j) {
    const int ci = j * 256 + wv * 64 + ln;
    const int row = ci >> 3;
    const int lc = (ci & 7) ^ (row & 7);
    gload16(Qh + ((size_t)bh * 1024 + q0 + row) * 64 + lc * 8,
            Qs + (size_t)(j * 256 + wv * 64) * 8);
  }
  __syncthreads();
  // hoisted Q fragments (B-operand: lane holds Q[q=col][kdim=quad*8+j])
  const half8 bq0 = frag_ld(Qs, wv * 16 + col, quad);
  const half8 bq1 = frag_ld(Qs, wv * 16 + col, 4 + quad);

  const f32x4 zero4 = {0.f, 0.f, 0.f, 0.f};
  f32x4 o[4];
#pragma unroll
  for (int ni = 0; ni < 4; ++ni) o[ni] = zero4;
  float m_i = -1e30f, l_i = 0.f;

  _Float16* Pw = Pt + wv * 1024;

  for (int k0 = 0; k0 < 1024; k0 += 64) {
    __syncthreads();
#pragma unroll
    for (int j = 0; j < 2; ++j) {
      const int ci = j * 256 + wv * 64 + ln;
      const int row = ci >> 3;
      const int lc = (ci & 7) ^ (row & 7);
      gload16(Kh + ((size_t)bh * 1024 + k0 + row) * 64 + lc * 8,
              Ks + (size_t)(j * 256 + wv * 64) * 8);
      gload16(Vt + ((size_t)(bh * 64 + row)) * 1024 + k0 + lc * 8,
              Vs + (size_t)(j * 256 + wv * 64) * 8);
    }
    // vectorized bias + mask loads (4 consecutive keys per reg) — overlap DMA
    f32x4 bb[4];
    int4 mk4[4];
#pragma unroll
    for (int mi = 0; mi < 4; ++mi) {
      const int kg = k0 + mi * 16 + quad * 4;
      mk4[mi] = *(const int4*)&kpm[b * 1024 + kg];
      bb[mi] = *(const f32x4*)&biasL[((size_t)(b * 1024 + qg)) * 1024 + kg];
    }
    __syncthreads();

    // S^T = K Q^T : s[mi][r] = S[k0+mi*16+quad*4+r][qg]
    f32x4 s[4];
#pragma unroll
    for (int mi = 0; mi < 4; ++mi) {
      f32x4 a4 = zero4;
      a4 = MFMA16(frag_ld(Ks, mi * 16 + col, quad), bq0, a4);
      a4 = MFMA16(frag_ld(Ks, mi * 16 + col, 4 + quad), bq1, a4);
      s[mi] = a4;
    }
#pragma unroll
    for (int mi = 0; mi < 4; ++mi) {
      const int* mp = (const int*)&mk4[mi];
#pragma unroll
      for (int r = 0; r < 4; ++r)
        s[mi][r] = mp[r] ? -1e9f : s[mi][r] * 0.125f + bb[mi][r];
    }

    // per-lane online softmax (row = qg), 2 shuffles per reduction
    float rm = -1e30f;
#pragma unroll
    for (int mi = 0; mi < 4; ++mi)
#pragma unroll
      for (int r = 0; r < 4; ++r) rm = fmaxf(rm, s[mi][r]);
    rm = fmaxf(rm, __shfl_xor(rm, 16));
    rm = fmaxf(rm, __shfl_xor(rm, 32));
    const float mn = fmaxf(m_i, rm);
    const float alpha = __expf(m_i - mn);
    m_i = mn;
    float ps = 0.f;
#pragma unroll
    for (int mi = 0; mi < 4; ++mi)
#pragma unroll
      for (int r = 0; r < 4; ++r) {
        const float p = __expf(s[mi][r] - mn);
        s[mi][r] = p;
        ps += p;
      }
    ps += __shfl_xor(ps, 16);
    ps += __shfl_xor(ps, 32);
    l_i = l_i * alpha + ps;
#pragma unroll
    for (int ni = 0; ni < 4; ++ni)
#pragma unroll
      for (int r = 0; r < 4; ++r) o[ni][r] *= alpha;

    // P^T -> per-wave LDS (row=q=col, 64 keys, swizzled); no barrier needed
#pragma unroll
    for (int mi = 0; mi < 4; ++mi) {
      half4_t h;
      h[0] = (_Float16)s[mi][0]; h[1] = (_Float16)s[mi][1];
      h[2] = (_Float16)s[mi][2]; h[3] = (_Float16)s[mi][3];
      const int kloc = mi * 16 + quad * 4;
      const int chunk = kloc >> 3;
      *(half4_t*)(Pw + col * 64 + (((chunk ^ (col & 7)) << 3) | (kloc & 7))) = h;
    }
    const half8 p0 = frag_ld(Pw, col, quad);
    const half8 p1 = frag_ld(Pw, col, 4 + quad);

    // O^T += V^T P^T
#pragma unroll
    for (int ni = 0; ni < 4; ++ni) {
      o[ni] = MFMA16(frag_ld(Vs, ni * 16 + col, quad), p0, o[ni]);
      o[ni] = MFMA16(frag_ld(Vs, ni * 16 + col, 4 + quad), p1, o[ni]);
    }
  }

  // epilogue: lane owns q=qg entirely; write half4 runs of dh
  const float inv = 1.0f / l_i;
#pragma unroll
  for (int ni = 0; ni < 4; ++ni) {
    half4_t h;
#pragma unroll
    for (int r = 0; r < 4; ++r) h[r] = (_Float16)(o[ni][r] * inv);
    *(half4_t*)&AO[((size_t)(b * 1024 + qg)) * 1024 + hh * 64 + ni * 16 + quad * 4] = h;
  }
}

extern "C" void kernel_launch(void* const* d_in, const int* in_sizes, int n_in,
                              void* d_out, int out_size, void* d_ws, size_t ws_size,
                              hipStream_t stream) {
  (void)in_sizes; (void)n_in; (void)out_size; (void)ws_size;
  const float* q = (const float*)d_in[0];
  const float* k = (const float*)d_in[1];
  const float* v = (const float*)d_in[2];
  const float* Wq = (const float*)d_in[3];
  const float* bq = (const float*)d_in[4];
  const float* Wk = (const float*)d_in[5];
  const float* bk = (const float*)d_in[6];
  const float* Wv = (const float*)d_in[7];
  const float* bv = (const float*)d_in[8];
  const float* Wo = (const float*)d_in[9];
  const float* bo = (const float*)d_in[10];
  const float* lb = (const float*)d_in[11];
  const int* kpm = (const int*)d_in[12];
  float* out = (float*)d_out;

  const size_t NT = (size_t)2 * 1024 * 1024;
  _Float16* q16 = (_Float16*)d_ws;
  _Float16* k16 = q16 + NT;
  _Float16* v16 = k16 + NT;
  _Float16* Qh = v16 + NT;
  _Float16* Kh = Qh + NT;
  _Float16* Vt = Kh + NT;
  _Float16* w16 = Vt + NT;  // 4 x 1M halves (Wq,Wk,Wv,Wo)
  _Float16* AO = q16;       // q16 dead after projections

  cvt_f32_f16<<<dim3(1024, 7), 256, 0, stream>>>(q, k, v, Wq, Wk, Wv, Wo,
                                                 q16, k16, v16, w16);
  mm_bt<<<dim3(8, 16, 3), 256, 0, stream>>>(q16, k16, v16, w16, bq, bk, bv,
                                            Qh, Kh, Vt, nullptr, 0);
  attn<<<dim3(16, 32), 256, 0, stream>>>(Qh, Kh, Vt, lb, kpm, AO);
  mm_bt<<<dim3(8, 16, 1), 256, 0, stream>>>(AO, nullptr, nullptr, w16 + 3 * NT / 2,
                                            bo, nullptr, nullptr, nullptr, nullptr,
                                            nullptr, out, 1);
}